// Round 9
// baseline (121.469 us; speedup 1.0000x reference)
//
#include <hip/hip_runtime.h>
#include <hip/hip_bf16.h>

// B=2, T=2048, C=1024, H=16, D=64
#define TB 2048
#define CC 1024
#define HH 16
#define DD 64
#define MM 4096     // B*T
#define N3 3072     // 3*C
#define KVB 128
#define NT (TB / KVB)   // 16

typedef __bf16 bf16x8 __attribute__((ext_vector_type(8)));
typedef float f32x4 __attribute__((ext_vector_type(4)));
typedef unsigned short ushort8 __attribute__((ext_vector_type(8)));
typedef unsigned short u16;

// q pre-scale: 0.125 * log2(e)  (softmax done in exp2 domain)
#define QSCALE 0.180336880693612f

__device__ __forceinline__ u16 f2b(float f) {
    unsigned int x = __float_as_uint(f);
    x = (x + 0x7fffu + ((x >> 16) & 1u)) >> 16;
    return (u16)x;
}

__device__ __forceinline__ unsigned cvt_pk_bf16(float lo, float hi) {
    unsigned r;
    asm("v_cvt_pk_bf16_f32 %0, %1, %2" : "=v"(r) : "v"(lo), "v"(hi));
    return r;
}

__device__ __forceinline__ void gld16(const u16* g, u16* l) {
    __builtin_amdgcn_global_load_lds(
        (const __attribute__((address_space(1))) unsigned int*)g,
        (__attribute__((address_space(3))) unsigned int*)l, 16, 0, 0);
}

// ---------- merged prep: fp32->bf16 convert (x) + both weight transposes ----------
__global__ __launch_bounds__(256) void prep(const float* __restrict__ x,
                                            u16* __restrict__ xb,
                                            const float* __restrict__ wqkv,
                                            u16* __restrict__ wqkvT,
                                            const float* __restrict__ wout,
                                            u16* __restrict__ woutT) {
    __shared__ float tl[64][65];
    const int bx = blockIdx.x;
    const int tid = threadIdx.x;
    if (bx < 4096) {
        int i = (bx * 256 + tid) * 4;
        float4 v = *reinterpret_cast<const float4*>(x + i);
        union { u16 u[4]; uint2 v2; } r;
        r.u[0] = f2b(v.x); r.u[1] = f2b(v.y); r.u[2] = f2b(v.z); r.u[3] = f2b(v.w);
        *reinterpret_cast<uint2*>(xb + i) = r.v2;
        return;
    }
    const int idx = bx - 4096;              // 0..1023
    const int nb = idx & 63, kb = idx >> 6; // n-tile, k-tile
    const float* in; u16* out; int N, n0;
    if (nb < 48) { in = wqkv; out = wqkvT; N = 3072; n0 = nb * 64; }
    else         { in = wout; out = woutT; N = 1024; n0 = (nb - 48) * 64; }
    const int k0 = kb * 64;
#pragma unroll
    for (int rep = 0; rep < 16; ++rep) {
        int id2 = rep * 256 + tid;
        int r = id2 >> 6, c = id2 & 63;
        tl[r][c] = in[(size_t)(k0 + r) * N + n0 + c];
    }
    __syncthreads();
#pragma unroll
    for (int rep = 0; rep < 16; ++rep) {
        int id2 = rep * 256 + tid;
        int r = id2 >> 6, c = id2 & 63;
        out[(size_t)(n0 + r) * 1024 + k0 + c] = f2b(tl[c][r]);
    }
}

// ---------- GEMM1: 128x128 tile, BK=64, global_load_lds + XOR swizzle ----------
// V third is written key-PERMUTED: within each 32-token block, token offset
// o = 16a+4h+r is stored at position 8h+4a+r (matches attn's PV A-fragment).
__global__ __launch_bounds__(256) void gemm_qkv(const u16* __restrict__ xb,   // [4096][1024]
                                                const u16* __restrict__ wT,   // [3072][1024]
                                                const float* __restrict__ bias,
                                                u16* __restrict__ qg,
                                                u16* __restrict__ kg,
                                                u16* __restrict__ vtg) {
    __shared__ u16 smem[2 * 128 * 64];           // As | Bs ; reused as [128][128] for V^T
    u16* As = smem;
    u16* Bs = smem + 128 * 64;
    const int m0 = blockIdx.y * 128, n0 = blockIdx.x * 128;
    const int tid = threadIdx.x;
    const int w = tid >> 6, lane = tid & 63, lr = lane & 15, h = lane >> 4;
    const int wr = w >> 1, wc = w & 1;
    f32x4 acc[4][4] = {};

    for (int k0 = 0; k0 < 1024; k0 += 64) {
        __syncthreads();
#pragma unroll
        for (int j = 0; j < 4; ++j) {
            int L = j * 256 + tid;
            int r = L >> 3, c = L & 7;
            int csw = (c ^ (r & 7)) << 3;
            gld16(xb + (size_t)(m0 + r) * 1024 + k0 + csw, As + L * 8);
            gld16(wT + (size_t)(n0 + r) * 1024 + k0 + csw, Bs + L * 8);
        }
        __syncthreads();
#pragma unroll
        for (int kk = 0; kk < 2; ++kk) {
            bf16x8 a[4], b[4];
            int cc = kk * 4 + h;
#pragma unroll
            for (int m = 0; m < 4; ++m) {
                int R = wr * 64 + m * 16 + lr;
                a[m] = *reinterpret_cast<const bf16x8*>((const char*)As + R * 128 + ((cc ^ (R & 7)) << 4));
            }
#pragma unroll
            for (int n = 0; n < 4; ++n) {
                int R = wc * 64 + n * 16 + lr;
                b[n] = *reinterpret_cast<const bf16x8*>((const char*)Bs + R * 128 + ((cc ^ (R & 7)) << 4));
            }
#pragma unroll
            for (int m = 0; m < 4; ++m)
#pragma unroll
                for (int n = 0; n < 4; ++n)
                    acc[m][n] = __builtin_amdgcn_mfma_f32_16x16x32_bf16(a[m], b[n], acc[m][n], 0, 0, 0);
        }
    }

    const int nthird = n0 >> 10;    // uniform per block (128 | 1024)
    if (nthird == 2) {
        // ---- V: transpose 128x128 subtile through LDS with key-permute ----
        __syncthreads();
#pragma unroll
        for (int n = 0; n < 4; ++n) {
            int nloc = wc * 64 + n * 16 + lr;
            unsigned xorv = (unsigned)(nloc & 15) << 4;
            float bv = bias[n0 + nloc];
#pragma unroll
            for (int m = 0; m < 4; ++m) {
                int mloc = wr * 64 + m * 16 + h * 4;
                // permuted position: o=16a+4h+r -> 8h+4a+r within 32-block
                int mp = (mloc & ~31) | (((mloc >> 2) & 3) << 3) | (((mloc >> 4) & 1) << 2);
                union { u16 u[4]; unsigned long long ll; } pk4;
#pragma unroll
                for (int reg = 0; reg < 4; ++reg)
                    pk4.u[reg] = f2b(acc[m][n][reg] + bv);
                *reinterpret_cast<unsigned long long*>(
                    (char*)smem + nloc * 256 + ((unsigned)(mp * 2) ^ xorv)) = pk4.ll;
            }
        }
        __syncthreads();
        const int b = m0 >> 11, t0 = m0 & 2047;
        const int c16 = tid & 15;
#pragma unroll
        for (int step = 0; step < 8; ++step) {
            int row = (tid >> 4) + step * 16;           // nloc 0..127
            ushort8 vch = *reinterpret_cast<const ushort8*>(
                (const char*)smem + row * 256 + ((unsigned)((c16 ^ (row & 15)) << 4)));
            int c1 = (n0 + row) & 1023;
            int hh = c1 >> 6, dd = c1 & 63;
            *reinterpret_cast<ushort8*>(
                vtg + ((size_t)(b * HH + hh) * DD + dd) * TB + t0 + c16 * 8) = vch;
        }
    } else {
#pragma unroll
        for (int n = 0; n < 4; ++n) {
            int ng = n0 + wc * 64 + n * 16 + lr;
            int c1 = ng & 1023;
            int hh = c1 >> 6, dd = c1 & 63;
            float bv = bias[ng];
#pragma unroll
            for (int m = 0; m < 4; ++m) {
#pragma unroll
                for (int reg = 0; reg < 4; ++reg) {
                    int mg = m0 + wr * 64 + m * 16 + h * 4 + reg;
                    int b = mg >> 11, t = mg & 2047;
                    size_t bh = (size_t)b * HH + hh;
                    float val = acc[m][n][reg] + bv;
                    if (nthird == 0) qg[(bh * TB + t) * DD + dd] = f2b(val * QSCALE);
                    else             kg[(bh * TB + t) * DD + dd] = f2b(val);
                }
            }
        }
    }
}

// ---------- flash attention: 8 waves, 128 q-rows, KVB=128, dbuf ----------
// R9: 2x-unrolled KV loop (compile-time buffer -> immediate LDS offsets),
// MFMA zero-init via persistent zero reg, incremental staging pointers.
__global__ __launch_bounds__(512, 4) void attn(const u16* __restrict__ qg,
                                               const u16* __restrict__ kg,
                                               const u16* __restrict__ vtg,
                                               u16* __restrict__ ao) {
    __shared__ u16 Kt[2][KVB * 64];   // [key][d], 128B rows, XOR-swizzled
    __shared__ u16 Vt[2][64 * KVB];   // [d][key-permuted], 256B rows, XOR-swizzled
    const int bh = blockIdx.y;
    const int q0 = blockIdx.x * 128;
    const int tid = threadIdx.x, w = tid >> 6, lane = tid & 63;
    const int lr = lane & 15, h = lane >> 4;
    const u16* qb = qg + (size_t)bh * TB * DD;
    const u16* kb = kg + (size_t)bh * TB * DD;
    const u16* vb = vtg + (size_t)bh * DD * TB;

#define STAGE(buf, kp, vp) do {                                                         \
    _Pragma("unroll")                                                                   \
    for (int j = 0; j < 2; ++j) {                                                       \
        int L = j * 512 + tid;                                                          \
        int rk = L >> 3, ck = L & 7;                                                    \
        gld16((kp) + (size_t)rk * DD + ((ck ^ (rk & 7)) << 3), Kt[buf] + L * 8);        \
        int rv = L >> 4, cv = L & 15;                                                   \
        gld16((vp) + (size_t)rv * TB + ((cv ^ (rv & 15)) << 3), Vt[buf] + L * 8);       \
    } } while (0)

    bf16x8 bq[2];
#pragma unroll
    for (int kk = 0; kk < 2; ++kk)
        bq[kk] = *reinterpret_cast<const bf16x8*>(qb + (size_t)(q0 + w * 16 + lr) * DD + kk * 32 + h * 8);

    f32x4 o[4] = {};          // o[ngd][reg] = O[qrow=h*4+reg][d=ngd*16+lr]
    float m_r = -1e30f;       // running max for qrow=lr (replicated across h)
    float l_r = 0.f;
    const f32x4 zero4 = {0.f, 0.f, 0.f, 0.f};

    auto tile_body = [&](const u16* ktc, const u16* vtc) {
        // S^T = K Q^T : s[ng][reg] = S[key=16ng+4h+reg][qrow=lr]
        f32x4 s[8];
        __builtin_amdgcn_s_setprio(1);
        {
            int cc0 = h;
#pragma unroll
            for (int ng = 0; ng < 8; ++ng) {
                int R = ng * 16 + lr;
                bf16x8 ak = *reinterpret_cast<const bf16x8*>((const char*)ktc + R * 128 + ((cc0 ^ (R & 7)) << 4));
                s[ng] = __builtin_amdgcn_mfma_f32_16x16x32_bf16(ak, bq[0], zero4, 0, 0, 0);
            }
            int cc1 = 4 + h;
#pragma unroll
            for (int ng = 0; ng < 8; ++ng) {
                int R = ng * 16 + lr;
                bf16x8 ak = *reinterpret_cast<const bf16x8*>((const char*)ktc + R * 128 + ((cc1 ^ (R & 7)) << 4));
                s[ng] = __builtin_amdgcn_mfma_f32_16x16x32_bf16(ak, bq[1], s[ng], 0, 0, 0);
            }
        }
        __builtin_amdgcn_s_setprio(0);

        // online softmax (exp2 domain), defer-max; tree reduces
        float tmx[8];
#pragma unroll
        for (int ng = 0; ng < 8; ++ng)
            tmx[ng] = fmaxf(fmaxf(s[ng][0], s[ng][1]), fmaxf(s[ng][2], s[ng][3]));
        float pm = fmaxf(fmaxf(fmaxf(tmx[0], tmx[1]), fmaxf(tmx[2], tmx[3])),
                         fmaxf(fmaxf(tmx[4], tmx[5]), fmaxf(tmx[6], tmx[7])));
        pm = fmaxf(pm, __shfl_xor(pm, 16));
        pm = fmaxf(pm, __shfl_xor(pm, 32));

        if (!__all(pm - m_r <= 8.0f)) {
            float mn = fmaxf(m_r, pm);
            float fr = __builtin_amdgcn_exp2f(m_r - mn);
            m_r = mn;
            l_r *= fr;
#pragma unroll
            for (int reg = 0; reg < 4; ++reg) {
                float fro = __shfl(fr, h * 4 + reg);
#pragma unroll
                for (int ngd = 0; ngd < 4; ++ngd)
                    o[ngd][reg] *= fro;
            }
        }

        float ps[8];
#pragma unroll
        for (int ng = 0; ng < 8; ++ng) {
            s[ng][0] = __builtin_amdgcn_exp2f(s[ng][0] - m_r);
            s[ng][1] = __builtin_amdgcn_exp2f(s[ng][1] - m_r);
            s[ng][2] = __builtin_amdgcn_exp2f(s[ng][2] - m_r);
            s[ng][3] = __builtin_amdgcn_exp2f(s[ng][3] - m_r);
            ps[ng] = (s[ng][0] + s[ng][1]) + (s[ng][2] + s[ng][3]);
        }
        float sum = ((ps[0] + ps[1]) + (ps[2] + ps[3])) + ((ps[4] + ps[5]) + (ps[6] + ps[7]));
        sum += __shfl_xor(sum, 16);
        sum += __shfl_xor(sum, 32);
        l_r += sum;

        // O += P V ; V rows are key-permuted so B-frag is one b128 per (kk,ngd)
        __builtin_amdgcn_s_setprio(1);
#pragma unroll
        for (int kk = 0; kk < 4; ++kk) {
            union { unsigned u[4]; bf16x8 v; } ap;
            ap.u[0] = cvt_pk_bf16(s[2 * kk][0], s[2 * kk][1]);
            ap.u[1] = cvt_pk_bf16(s[2 * kk][2], s[2 * kk][3]);
            ap.u[2] = cvt_pk_bf16(s[2 * kk + 1][0], s[2 * kk + 1][1]);
            ap.u[3] = cvt_pk_bf16(s[2 * kk + 1][2], s[2 * kk + 1][3]);
            int cpos = kk * 4 + h;
#pragma unroll
            for (int ngd = 0; ngd < 4; ++ngd) {
                int d = ngd * 16 + lr;
                bf16x8 bv = *reinterpret_cast<const bf16x8*>((const char*)vtc + d * 256 + ((cpos ^ (d & 15)) << 4));
                o[ngd] = __builtin_amdgcn_mfma_f32_16x16x32_bf16(ap.v, bv, o[ngd], 0, 0, 0);
            }
        }
        __builtin_amdgcn_s_setprio(0);
    };

    STAGE(0, kb, vb);
    const u16* kp = kb + KVB * DD;
    const u16* vp = vb + KVB;
    __syncthreads();

#pragma unroll 1
    for (int kt2 = 0; kt2 < NT / 2; ++kt2) {
        // even tile (buf 0): prefetch next into buf 1
        STAGE(1, kp, vp);
        kp += KVB * DD; vp += KVB;
        tile_body(Kt[0], Vt[0]);
        __syncthreads();
        // odd tile (buf 1): prefetch next into buf 0
        if (kt2 < NT / 2 - 1) {
            STAGE(0, kp, vp);
            kp += KVB * DD; vp += KVB;
        }
        tile_body(Kt[1], Vt[1]);
        __syncthreads();
    }
#undef STAGE

    float linv[4];
#pragma unroll
    for (int reg = 0; reg < 4; ++reg)
        linv[reg] = 1.0f / __shfl(l_r, h * 4 + reg);

    const int b = bh >> 4, hh = bh & 15;
#pragma unroll
    for (int ngd = 0; ngd < 4; ++ngd) {
#pragma unroll
        for (int reg = 0; reg < 4; ++reg) {
            int t = q0 + w * 16 + h * 4 + reg;
            int col = hh * DD + ngd * 16 + lr;
            ao[((size_t)(b * TB + t)) * CC + col] = f2b(o[ngd][reg] * linv[reg]);
        }
    }
}

// ---------- GEMM2: out = ao @ W_out + b_out, BM=64 BN=128 (2 blocks/CU) ----------
__global__ __launch_bounds__(256) void gemm_out(const u16* __restrict__ ao,   // [4096][1024]
                                                const u16* __restrict__ wT,   // [1024][1024]
                                                const float* __restrict__ bias,
                                                float* __restrict__ out) {
    __shared__ u16 As[64 * 64];
    __shared__ u16 Bs[128 * 64];
    const int m0 = blockIdx.y * 64, n0 = blockIdx.x * 128;
    const int tid = threadIdx.x;
    const int w = tid >> 6, lane = tid & 63, lr = lane & 15, h = lane >> 4;
    f32x4 acc[4][2] = {};

    for (int k0 = 0; k0 < 1024; k0 += 64) {
        __syncthreads();
#pragma unroll
        for (int j = 0; j < 2; ++j) {
            int L = j * 256 + tid;
            int r = L >> 3, c = L & 7;
            gld16(ao + (size_t)(m0 + r) * 1024 + k0 + ((c ^ (r & 7)) << 3), As + L * 8);
        }
#pragma unroll
        for (int j = 0; j < 4; ++j) {
            int L = j * 256 + tid;
            int r = L >> 3, c = L & 7;
            gld16(wT + (size_t)(n0 + r) * 1024 + k0 + ((c ^ (r & 7)) << 3), Bs + L * 8);
        }
        __syncthreads();
#pragma unroll
        for (int kk = 0; kk < 2; ++kk) {
            bf16x8 a[4], b[2];
            int cc = kk * 4 + h;
#pragma unroll
            for (int m = 0; m < 4; ++m) {
                int R = m * 16 + lr;
                a[m] = *reinterpret_cast<const bf16x8*>((const char*)As + R * 128 + ((cc ^ (R & 7)) << 4));
            }
#pragma unroll
            for (int n = 0; n < 2; ++n) {
                int R = w * 32 + n * 16 + lr;
                b[n] = *reinterpret_cast<const bf16x8*>((const char*)Bs + R * 128 + ((cc ^ (R & 7)) << 4));
            }
#pragma unroll
            for (int m = 0; m < 4; ++m)
#pragma unroll
                for (int n = 0; n < 2; ++n)
                    acc[m][n] = __builtin_amdgcn_mfma_f32_16x16x32_bf16(a[m], b[n], acc[m][n], 0, 0, 0);
        }
    }

#pragma unroll
    for (int n = 0; n < 2; ++n) {
        int ng = n0 + w * 32 + n * 16 + lr;
        float bv = bias[ng];
#pragma unroll
        for (int m = 0; m < 4; ++m) {
#pragma unroll
            for (int reg = 0; reg < 4; ++reg) {
                int mg = m0 + m * 16 + h * 4 + reg;
                out[(size_t)mg * 1024 + ng] = acc[m][n][reg] + bv;
            }
        }
    }
}

extern "C" void kernel_launch(void* const* d_in, const int* in_sizes, int n_in,
                              void* d_out, int out_size, void* d_ws, size_t ws_size,
                              hipStream_t stream) {
    const float* x     = (const float*)d_in[0];
    const float* W_qkv = (const float*)d_in[1];
    const float* b_qkv = (const float*)d_in[2];
    const float* W_out = (const float*)d_in[3];
    const float* b_out = (const float*)d_in[4];
    float* out = (float*)d_out;

    char* ws = (char*)d_ws;
    u16* xb    = (u16*)(ws);                       // 8 MB  x bf16 [4096][1024]
    u16* wqkvT = (u16*)(ws + (size_t)( 8u << 20)); // 6 MB  W_qkv^T bf16 [3072][1024]
    u16* woutT = (u16*)(ws + (size_t)(14u << 20)); // 2 MB  W_out^T bf16 [1024][1024]
    u16* qg    = (u16*)(ws + (size_t)(16u << 20)); // 8 MB  Q [B,H,T,D] (pre-scaled)
    u16* kg    = (u16*)(ws + (size_t)(24u << 20)); // 8 MB  K [B,H,T,D]
    u16* vtg   = (u16*)(ws + (size_t)(32u << 20)); // 8 MB  V^T [B,H,D,T] key-permuted
    u16* ao    = xb;                               // reuse x buffer for attn-out

    hipLaunchKernelGGL(prep, dim3(5120), dim3(256), 0, stream, x, xb, W_qkv, wqkvT, W_out, woutT);
    hipLaunchKernelGGL(gemm_qkv, dim3(24, 32), dim3(256), 0, stream, xb, wqkvT, b_qkv, qg, kg, vtg);
    hipLaunchKernelGGL(attn, dim3(16, 32), dim3(512), 0, stream, qg, kg, vtg, ao);
    hipLaunchKernelGGL(gemm_out, dim3(8, 64), dim3(256), 0, stream, ao, woutT, b_out, out);
}

// Round 10
// 118.425 us; speedup vs baseline: 1.0257x; 1.0257x over previous
//
#include <hip/hip_runtime.h>
#include <hip/hip_bf16.h>

// B=2, T=2048, C=1024, H=16, D=64
#define TB 2048
#define CC 1024
#define HH 16
#define DD 64
#define MM 4096     // B*T
#define N3 3072     // 3*C
#define KVB 128
#define NT (TB / KVB)   // 16

typedef __bf16 bf16x8 __attribute__((ext_vector_type(8)));
typedef float f32x4 __attribute__((ext_vector_type(4)));
typedef unsigned short ushort8 __attribute__((ext_vector_type(8)));
typedef unsigned short u16;

// q pre-scale: 0.125 * log2(e)  (softmax done in exp2 domain)
#define QSCALE 0.180336880693612f

__device__ __forceinline__ u16 f2b(float f) {
    unsigned int x = __float_as_uint(f);
    x = (x + 0x7fffu + ((x >> 16) & 1u)) >> 16;
    return (u16)x;
}

__device__ __forceinline__ unsigned cvt_pk_bf16(float lo, float hi) {
    unsigned r;
    asm("v_cvt_pk_bf16_f32 %0, %1, %2" : "=v"(r) : "v"(lo), "v"(hi));
    return r;
}

__device__ __forceinline__ void gld16(const u16* g, u16* l) {
    __builtin_amdgcn_global_load_lds(
        (const __attribute__((address_space(1))) unsigned int*)g,
        (__attribute__((address_space(3))) unsigned int*)l, 16, 0, 0);
}

// ---------- merged prep: fp32->bf16 convert (x) + both weight transposes ----------
__global__ __launch_bounds__(256) void prep(const float* __restrict__ x,
                                            u16* __restrict__ xb,
                                            const float* __restrict__ wqkv,
                                            u16* __restrict__ wqkvT,
                                            const float* __restrict__ wout,
                                            u16* __restrict__ woutT) {
    __shared__ float tl[64][65];
    const int bx = blockIdx.x;
    const int tid = threadIdx.x;
    if (bx < 4096) {
        int i = (bx * 256 + tid) * 4;
        float4 v = *reinterpret_cast<const float4*>(x + i);
        union { u16 u[4]; uint2 v2; } r;
        r.u[0] = f2b(v.x); r.u[1] = f2b(v.y); r.u[2] = f2b(v.z); r.u[3] = f2b(v.w);
        *reinterpret_cast<uint2*>(xb + i) = r.v2;
        return;
    }
    const int idx = bx - 4096;              // 0..1023
    const int nb = idx & 63, kb = idx >> 6; // n-tile, k-tile
    const float* in; u16* out; int N, n0;
    if (nb < 48) { in = wqkv; out = wqkvT; N = 3072; n0 = nb * 64; }
    else         { in = wout; out = woutT; N = 1024; n0 = (nb - 48) * 64; }
    const int k0 = kb * 64;
#pragma unroll
    for (int rep = 0; rep < 16; ++rep) {
        int id2 = rep * 256 + tid;
        int r = id2 >> 6, c = id2 & 63;
        tl[r][c] = in[(size_t)(k0 + r) * N + n0 + c];
    }
    __syncthreads();
#pragma unroll
    for (int rep = 0; rep < 16; ++rep) {
        int id2 = rep * 256 + tid;
        int r = id2 >> 6, c = id2 & 63;
        out[(size_t)(n0 + r) * 1024 + k0 + c] = f2b(tl[c][r]);
    }
}

// ---------- GEMM1: 128x128 tile, BK=64, global_load_lds + XOR swizzle ----------
// V third written key-PERMUTED (matches attn PV A-fragment); Q/K thirds now
// also routed through LDS transpose for coalesced 16B stores (R10).
__global__ __launch_bounds__(256) void gemm_qkv(const u16* __restrict__ xb,   // [4096][1024]
                                                const u16* __restrict__ wT,   // [3072][1024]
                                                const float* __restrict__ bias,
                                                u16* __restrict__ qg,
                                                u16* __restrict__ kg,
                                                u16* __restrict__ vtg) {
    __shared__ u16 smem[2 * 128 * 64];           // As | Bs ; reused as [128][128] epilogue
    u16* As = smem;
    u16* Bs = smem + 128 * 64;
    const int m0 = blockIdx.y * 128, n0 = blockIdx.x * 128;
    const int tid = threadIdx.x;
    const int w = tid >> 6, lane = tid & 63, lr = lane & 15, h = lane >> 4;
    const int wr = w >> 1, wc = w & 1;
    f32x4 acc[4][4] = {};

    for (int k0 = 0; k0 < 1024; k0 += 64) {
        __syncthreads();
#pragma unroll
        for (int j = 0; j < 4; ++j) {
            int L = j * 256 + tid;
            int r = L >> 3, c = L & 7;
            int csw = (c ^ (r & 7)) << 3;
            gld16(xb + (size_t)(m0 + r) * 1024 + k0 + csw, As + L * 8);
            gld16(wT + (size_t)(n0 + r) * 1024 + k0 + csw, Bs + L * 8);
        }
        __syncthreads();
#pragma unroll
        for (int kk = 0; kk < 2; ++kk) {
            bf16x8 a[4], b[4];
            int cc = kk * 4 + h;
#pragma unroll
            for (int m = 0; m < 4; ++m) {
                int R = wr * 64 + m * 16 + lr;
                a[m] = *reinterpret_cast<const bf16x8*>((const char*)As + R * 128 + ((cc ^ (R & 7)) << 4));
            }
#pragma unroll
            for (int n = 0; n < 4; ++n) {
                int R = wc * 64 + n * 16 + lr;
                b[n] = *reinterpret_cast<const bf16x8*>((const char*)Bs + R * 128 + ((cc ^ (R & 7)) << 4));
            }
#pragma unroll
            for (int m = 0; m < 4; ++m)
#pragma unroll
                for (int n = 0; n < 4; ++n)
                    acc[m][n] = __builtin_amdgcn_mfma_f32_16x16x32_bf16(a[m], b[n], acc[m][n], 0, 0, 0);
        }
    }

    const int nthird = n0 >> 10;    // uniform per block (128 | 1024)
    const int b = m0 >> 11, t0 = m0 & 2047;
    if (nthird == 2) {
        // ---- V: transpose 128x128 subtile through LDS with key-permute ----
        __syncthreads();
#pragma unroll
        for (int n = 0; n < 4; ++n) {
            int nloc = wc * 64 + n * 16 + lr;
            unsigned xorv = (unsigned)(nloc & 15) << 4;
            float bv = bias[n0 + nloc];
#pragma unroll
            for (int m = 0; m < 4; ++m) {
                int mloc = wr * 64 + m * 16 + h * 4;
                // permuted position: o=16a+4h+r -> 8h+4a+r within 32-block
                int mp = (mloc & ~31) | (((mloc >> 2) & 3) << 3) | (((mloc >> 4) & 1) << 2);
                union { u16 u[4]; unsigned long long ll; } pk4;
#pragma unroll
                for (int reg = 0; reg < 4; ++reg)
                    pk4.u[reg] = f2b(acc[m][n][reg] + bv);
                *reinterpret_cast<unsigned long long*>(
                    (char*)smem + nloc * 256 + ((unsigned)(mp * 2) ^ xorv)) = pk4.ll;
            }
        }
        __syncthreads();
        const int c16 = tid & 15;
#pragma unroll
        for (int step = 0; step < 8; ++step) {
            int row = (tid >> 4) + step * 16;           // nloc 0..127
            ushort8 vch = *reinterpret_cast<const ushort8*>(
                (const char*)smem + row * 256 + ((unsigned)((c16 ^ (row & 15)) << 4)));
            int c1 = (n0 + row) & 1023;
            int hh = c1 >> 6, dd = c1 & 63;
            *reinterpret_cast<ushort8*>(
                vtg + ((size_t)(b * HH + hh) * DD + dd) * TB + t0 + c16 * 8) = vch;
        }
    } else {
        // ---- Q/K: transpose-free LDS round-trip for coalesced 16B stores ----
        const float qs = (nthird == 0) ? QSCALE : 1.0f;
        __syncthreads();
#pragma unroll
        for (int n = 0; n < 4; ++n) {
            int nloc = wc * 64 + n * 16 + lr;
            float bv = bias[n0 + nloc];
#pragma unroll
            for (int m = 0; m < 4; ++m) {
#pragma unroll
                for (int reg = 0; reg < 4; ++reg) {
                    int mloc = wr * 64 + m * 16 + h * 4 + reg;
                    *reinterpret_cast<u16*>((char*)smem + mloc * 256 +
                        ((unsigned)(nloc * 2) ^ ((unsigned)(mloc & 15) << 4)))
                        = f2b((acc[m][n][reg] + bv) * qs);
                }
            }
        }
        __syncthreads();
        u16* dst = (nthird == 0) ? qg : kg;
        const int c16 = tid & 15;
#pragma unroll
        for (int step = 0; step < 8; ++step) {
            int row = (tid >> 4) + step * 16;           // mloc 0..127 (t index)
            ushort8 vch = *reinterpret_cast<const ushort8*>(
                (const char*)smem + row * 256 + ((unsigned)((c16 ^ (row & 15)) << 4)));
            int colbase = c16 * 8;                      // 0..120
            int c1 = (n0 + colbase) & 1023;
            int hh = c1 >> 6, dd = c1 & 63;
            *reinterpret_cast<ushort8*>(
                dst + ((size_t)(b * HH + hh) * TB + (t0 + row)) * DD + dd) = vch;
        }
    }
}

// ---------- flash attention: 8 waves, 128 q-rows, KVB=128, dbuf ----------
// R10: grid swapped to (x=bh, y=q-block) so all q-blocks of one head land on
// one XCD (linear id % 8 == bh % 8) -> K/V L2-resident per XCD.
__global__ __launch_bounds__(512, 4) void attn(const u16* __restrict__ qg,
                                               const u16* __restrict__ kg,
                                               const u16* __restrict__ vtg,
                                               u16* __restrict__ ao) {
    __shared__ u16 Kt[2][KVB * 64];   // [key][d], 128B rows, XOR-swizzled
    __shared__ u16 Vt[2][64 * KVB];   // [d][key-permuted], 256B rows, XOR-swizzled
    const int bh = blockIdx.x;
    const int q0 = blockIdx.y * 128;
    const int tid = threadIdx.x, w = tid >> 6, lane = tid & 63;
    const int lr = lane & 15, h = lane >> 4;
    const u16* qb = qg + (size_t)bh * TB * DD;
    const u16* kb = kg + (size_t)bh * TB * DD;
    const u16* vb = vtg + (size_t)bh * DD * TB;

#define STAGE(buf, kp, vp) do {                                                         \
    _Pragma("unroll")                                                                   \
    for (int j = 0; j < 2; ++j) {                                                       \
        int L = j * 512 + tid;                                                          \
        int rk = L >> 3, ck = L & 7;                                                    \
        gld16((kp) + (size_t)rk * DD + ((ck ^ (rk & 7)) << 3), Kt[buf] + L * 8);        \
        int rv = L >> 4, cv = L & 15;                                                   \
        gld16((vp) + (size_t)rv * TB + ((cv ^ (rv & 15)) << 3), Vt[buf] + L * 8);       \
    } } while (0)

    bf16x8 bq[2];
#pragma unroll
    for (int kk = 0; kk < 2; ++kk)
        bq[kk] = *reinterpret_cast<const bf16x8*>(qb + (size_t)(q0 + w * 16 + lr) * DD + kk * 32 + h * 8);

    f32x4 o[4] = {};          // o[ngd][reg] = O[qrow=h*4+reg][d=ngd*16+lr]
    float m_r = -1e30f;       // running max for qrow=lr (replicated across h)
    float l_r = 0.f;
    const f32x4 zero4 = {0.f, 0.f, 0.f, 0.f};

    auto tile_body = [&](const u16* ktc, const u16* vtc) {
        // S^T = K Q^T : s[ng][reg] = S[key=16ng+4h+reg][qrow=lr]
        f32x4 s[8];
        __builtin_amdgcn_s_setprio(1);
        {
            int cc0 = h;
#pragma unroll
            for (int ng = 0; ng < 8; ++ng) {
                int R = ng * 16 + lr;
                bf16x8 ak = *reinterpret_cast<const bf16x8*>((const char*)ktc + R * 128 + ((cc0 ^ (R & 7)) << 4));
                s[ng] = __builtin_amdgcn_mfma_f32_16x16x32_bf16(ak, bq[0], zero4, 0, 0, 0);
            }
            int cc1 = 4 + h;
#pragma unroll
            for (int ng = 0; ng < 8; ++ng) {
                int R = ng * 16 + lr;
                bf16x8 ak = *reinterpret_cast<const bf16x8*>((const char*)ktc + R * 128 + ((cc1 ^ (R & 7)) << 4));
                s[ng] = __builtin_amdgcn_mfma_f32_16x16x32_bf16(ak, bq[1], s[ng], 0, 0, 0);
            }
        }
        __builtin_amdgcn_s_setprio(0);

        // online softmax (exp2 domain), defer-max; tree reduces
        float tmx[8];
#pragma unroll
        for (int ng = 0; ng < 8; ++ng)
            tmx[ng] = fmaxf(fmaxf(s[ng][0], s[ng][1]), fmaxf(s[ng][2], s[ng][3]));
        float pm = fmaxf(fmaxf(fmaxf(tmx[0], tmx[1]), fmaxf(tmx[2], tmx[3])),
                         fmaxf(fmaxf(tmx[4], tmx[5]), fmaxf(tmx[6], tmx[7])));
        pm = fmaxf(pm, __shfl_xor(pm, 16));
        pm = fmaxf(pm, __shfl_xor(pm, 32));

        if (!__all(pm - m_r <= 8.0f)) {
            float mn = fmaxf(m_r, pm);
            float fr = __builtin_amdgcn_exp2f(m_r - mn);
            m_r = mn;
            l_r *= fr;
#pragma unroll
            for (int reg = 0; reg < 4; ++reg) {
                float fro = __shfl(fr, h * 4 + reg);
#pragma unroll
                for (int ngd = 0; ngd < 4; ++ngd)
                    o[ngd][reg] *= fro;
            }
        }

        float ps[8];
#pragma unroll
        for (int ng = 0; ng < 8; ++ng) {
            s[ng][0] = __builtin_amdgcn_exp2f(s[ng][0] - m_r);
            s[ng][1] = __builtin_amdgcn_exp2f(s[ng][1] - m_r);
            s[ng][2] = __builtin_amdgcn_exp2f(s[ng][2] - m_r);
            s[ng][3] = __builtin_amdgcn_exp2f(s[ng][3] - m_r);
            ps[ng] = (s[ng][0] + s[ng][1]) + (s[ng][2] + s[ng][3]);
        }
        float sum = ((ps[0] + ps[1]) + (ps[2] + ps[3])) + ((ps[4] + ps[5]) + (ps[6] + ps[7]));
        sum += __shfl_xor(sum, 16);
        sum += __shfl_xor(sum, 32);
        l_r += sum;

        // O += P V ; V rows are key-permuted so B-frag is one b128 per (kk,ngd)
        __builtin_amdgcn_s_setprio(1);
#pragma unroll
        for (int kk = 0; kk < 4; ++kk) {
            union { unsigned u[4]; bf16x8 v; } ap;
            ap.u[0] = cvt_pk_bf16(s[2 * kk][0], s[2 * kk][1]);
            ap.u[1] = cvt_pk_bf16(s[2 * kk][2], s[2 * kk][3]);
            ap.u[2] = cvt_pk_bf16(s[2 * kk + 1][0], s[2 * kk + 1][1]);
            ap.u[3] = cvt_pk_bf16(s[2 * kk + 1][2], s[2 * kk + 1][3]);
            int cpos = kk * 4 + h;
#pragma unroll
            for (int ngd = 0; ngd < 4; ++ngd) {
                int d = ngd * 16 + lr;
                bf16x8 bv = *reinterpret_cast<const bf16x8*>((const char*)vtc + d * 256 + ((cpos ^ (d & 15)) << 4));
                o[ngd] = __builtin_amdgcn_mfma_f32_16x16x32_bf16(ap.v, bv, o[ngd], 0, 0, 0);
            }
        }
        __builtin_amdgcn_s_setprio(0);
    };

    STAGE(0, kb, vb);
    const u16* kp = kb + KVB * DD;
    const u16* vp = vb + KVB;
    __syncthreads();

#pragma unroll 1
    for (int kt2 = 0; kt2 < NT / 2; ++kt2) {
        // even tile (buf 0): prefetch next into buf 1
        STAGE(1, kp, vp);
        kp += KVB * DD; vp += KVB;
        tile_body(Kt[0], Vt[0]);
        __syncthreads();
        // odd tile (buf 1): prefetch next into buf 0
        if (kt2 < NT / 2 - 1) {
            STAGE(0, kp, vp);
            kp += KVB * DD; vp += KVB;
        }
        tile_body(Kt[1], Vt[1]);
        __syncthreads();
    }
#undef STAGE

    float linv[4];
#pragma unroll
    for (int reg = 0; reg < 4; ++reg)
        linv[reg] = 1.0f / __shfl(l_r, h * 4 + reg);

    const int b = bh >> 4, hh = bh & 15;
#pragma unroll
    for (int ngd = 0; ngd < 4; ++ngd) {
#pragma unroll
        for (int reg = 0; reg < 4; ++reg) {
            int t = q0 + w * 16 + h * 4 + reg;
            int col = hh * DD + ngd * 16 + lr;
            ao[((size_t)(b * TB + t)) * CC + col] = f2b(o[ngd][reg] * linv[reg]);
        }
    }
}

// ---------- GEMM2: out = ao @ W_out + b_out, BM=64 BN=128 (2 blocks/CU) ----------
__global__ __launch_bounds__(256) void gemm_out(const u16* __restrict__ ao,   // [4096][1024]
                                                const u16* __restrict__ wT,   // [1024][1024]
                                                const float* __restrict__ bias,
                                                float* __restrict__ out) {
    __shared__ u16 As[64 * 64];
    __shared__ u16 Bs[128 * 64];
    const int m0 = blockIdx.y * 64, n0 = blockIdx.x * 128;
    const int tid = threadIdx.x;
    const int w = tid >> 6, lane = tid & 63, lr = lane & 15, h = lane >> 4;
    f32x4 acc[4][2] = {};

    for (int k0 = 0; k0 < 1024; k0 += 64) {
        __syncthreads();
#pragma unroll
        for (int j = 0; j < 2; ++j) {
            int L = j * 256 + tid;
            int r = L >> 3, c = L & 7;
            gld16(ao + (size_t)(m0 + r) * 1024 + k0 + ((c ^ (r & 7)) << 3), As + L * 8);
        }
#pragma unroll
        for (int j = 0; j < 4; ++j) {
            int L = j * 256 + tid;
            int r = L >> 3, c = L & 7;
            gld16(wT + (size_t)(n0 + r) * 1024 + k0 + ((c ^ (r & 7)) << 3), Bs + L * 8);
        }
        __syncthreads();
#pragma unroll
        for (int kk = 0; kk < 2; ++kk) {
            bf16x8 a[4], b[2];
            int cc = kk * 4 + h;
#pragma unroll
            for (int m = 0; m < 4; ++m) {
                int R = m * 16 + lr;
                a[m] = *reinterpret_cast<const bf16x8*>((const char*)As + R * 128 + ((cc ^ (R & 7)) << 4));
            }
#pragma unroll
            for (int n = 0; n < 2; ++n) {
                int R = w * 32 + n * 16 + lr;
                b[n] = *reinterpret_cast<const bf16x8*>((const char*)Bs + R * 128 + ((cc ^ (R & 7)) << 4));
            }
#pragma unroll
            for (int m = 0; m < 4; ++m)
#pragma unroll
                for (int n = 0; n < 2; ++n)
                    acc[m][n] = __builtin_amdgcn_mfma_f32_16x16x32_bf16(a[m], b[n], acc[m][n], 0, 0, 0);
        }
    }

#pragma unroll
    for (int n = 0; n < 2; ++n) {
        int ng = n0 + w * 32 + n * 16 + lr;
        float bv = bias[ng];
#pragma unroll
        for (int m = 0; m < 4; ++m) {
#pragma unroll
            for (int reg = 0; reg < 4; ++reg) {
                int mg = m0 + m * 16 + h * 4 + reg;
                out[(size_t)mg * 1024 + ng] = acc[m][n][reg] + bv;
            }
        }
    }
}

extern "C" void kernel_launch(void* const* d_in, const int* in_sizes, int n_in,
                              void* d_out, int out_size, void* d_ws, size_t ws_size,
                              hipStream_t stream) {
    const float* x     = (const float*)d_in[0];
    const float* W_qkv = (const float*)d_in[1];
    const float* b_qkv = (const float*)d_in[2];
    const float* W_out = (const float*)d_in[3];
    const float* b_out = (const float*)d_in[4];
    float* out = (float*)d_out;

    char* ws = (char*)d_ws;
    u16* xb    = (u16*)(ws);                       // 8 MB  x bf16 [4096][1024]
    u16* wqkvT = (u16*)(ws + (size_t)( 8u << 20)); // 6 MB  W_qkv^T bf16 [3072][1024]
    u16* woutT = (u16*)(ws + (size_t)(14u << 20)); // 2 MB  W_out^T bf16 [1024][1024]
    u16* qg    = (u16*)(ws + (size_t)(16u << 20)); // 8 MB  Q [B,H,T,D] (pre-scaled)
    u16* kg    = (u16*)(ws + (size_t)(24u << 20)); // 8 MB  K [B,H,T,D]
    u16* vtg   = (u16*)(ws + (size_t)(32u << 20)); // 8 MB  V^T [B,H,D,T] key-permuted
    u16* ao    = xb;                               // reuse x buffer for attn-out

    hipLaunchKernelGGL(prep, dim3(5120), dim3(256), 0, stream, x, xb, W_qkv, wqkvT, W_out, woutT);
    hipLaunchKernelGGL(gemm_qkv, dim3(24, 32), dim3(256), 0, stream, xb, wqkvT, b_qkv, qg, kg, vtg);
    hipLaunchKernelGGL(attn, dim3(32, 16), dim3(512), 0, stream, qg, kg, vtg, ao);
    hipLaunchKernelGGL(gemm_out, dim3(8, 64), dim3(256), 0, stream, ao, woutT, b_out, out);
}